// Round 1
// baseline (52.565 us; speedup 1.0000x reference)
//
#include <hip/hip_runtime.h>

#define BB 32
#define NT 1024
#define SS 4096
#define DD 512
#define D4 128  // DD/4

typedef float f32x4 __attribute__((ext_vector_type(4)));

// Per-sample params: L (text length), base, r, split
__global__ void prep_kernel(const int* __restrict__ text,
                            const int* __restrict__ seq_len,
                            int4* __restrict__ params) {
    int b = blockIdx.x;
    int tid = threadIdx.x;
    int cnt = 0;
    for (int k = tid; k < NT; k += 256)
        cnt += (text[b * NT + k] >= 0) ? 1 : 0;
    // wave64 reduce
    for (int off = 32; off > 0; off >>= 1)
        cnt += __shfl_down(cnt, off);
    __shared__ int s[4];
    if ((tid & 63) == 0) s[tid >> 6] = cnt;
    __syncthreads();
    if (tid == 0) {
        int L = s[0] + s[1] + s[2] + s[3];
        int A = seq_len[b];
        int Ls = (L > 0) ? L : 1;
        int base = A / Ls;
        int rr = A - base * Ls;
        int split = (L - rr) * base;
        params[b] = make_int4(L, base, rr, split);
    }
}

__global__ void __launch_bounds__(256) upsample_kernel(
        const int* __restrict__ text,
        const int* __restrict__ seq_len,
        const f32x4* __restrict__ W4,     // [(VOCAB+1) * D4]
        const int4* __restrict__ params,
        f32x4* __restrict__ out4) {
    int idx = blockIdx.x * 256 + threadIdx.x;
    int d4  = idx & (D4 - 1);
    int row = idx >> 7;            // b*S + t
    int t   = row & (SS - 1);
    int b   = row >> 12;

    int A = seq_len[b];
    f32x4 v = (f32x4)(0.0f);
    if (t < A) {
        int4 p = params[b];
        int L = p.x, base = p.y, rr = p.z, split = p.w;
        if (L > 0) {
            int j;
            if (t < split) {
                int bb = (base > 0) ? base : 1;
                j = t / bb;
            } else {
                j = (L - rr) + (t - split) / (base + 1);
            }
            if (j > SS - 1) j = SS - 1;
            if (j < 0) j = 0;
            // j < L <= NT here by construction, so text[b*NT+j] is valid
            int tok = text[b * NT + j] + 1;
            v = W4[(long)tok * D4 + d4];
        }
    }
    __builtin_nontemporal_store(v, &out4[idx]);
}

extern "C" void kernel_launch(void* const* d_in, const int* in_sizes, int n_in,
                              void* d_out, int out_size, void* d_ws, size_t ws_size,
                              hipStream_t stream) {
    const int* text    = (const int*)d_in[0];
    const int* seq_len = (const int*)d_in[1];
    const f32x4* W4    = (const f32x4*)d_in[2];
    f32x4* out4        = (f32x4*)d_out;
    int4* params       = (int4*)d_ws;

    prep_kernel<<<BB, 256, 0, stream>>>(text, seq_len, params);

    // one thread per float4 of output: B*S*D4 threads
    int total = BB * SS * D4;            // 16,777,216
    upsample_kernel<<<total / 256, 256, 0, stream>>>(text, seq_len, W4, params, out4);
}

// Round 2
// 45.869 us; speedup vs baseline: 1.1460x; 1.1460x over previous
//
#include <hip/hip_runtime.h>

#define BB 32
#define NTT 1024
#define SS 4096
#define D4 128   // D/4 = 512/4

typedef float f32x4 __attribute__((ext_vector_type(4)));

// One wave = one output row [D=512] = 64 lanes x 2 float4.
// L (valid text length) found per-wave via 2-round probe+ballot over the
// contiguous non-negative prefix of text[b].
__global__ void __launch_bounds__(256) fused_upsample_kernel(
        const int* __restrict__ text,
        const int* __restrict__ seq_len,
        const f32x4* __restrict__ W4,     // [(VOCAB+1) * D4]
        f32x4* __restrict__ out4) {
    int wid  = (blockIdx.x << 2) + (threadIdx.x >> 6);  // global wave id = row id
    int lane = threadIdx.x & 63;
    int t = wid & (SS - 1);
    int b = wid >> 12;

    const int* trow = text + b * NTT;

    // ---- round 1: probe every 16th position (covers 0..1008) ----
    int v1 = trow[lane << 4];
    unsigned long long m1 = __ballot(v1 < 0);
    int lo;
    if (m1 == 0ull) {
        lo = NTT - 16;                    // first negative (if any) in (1008, 1024)
    } else {
        int p = __builtin_ctzll(m1);
        lo = (p == 0) ? 0 : ((p - 1) << 4);
    }
    // ---- round 2: probe lo..lo+63 (virtual -1 beyond NT) ----
    int k2 = lo + lane;
    int v2 = (k2 < NTT) ? trow[k2] : -1;
    unsigned long long m2 = __ballot(v2 < 0);
    int L = lo + __builtin_ctzll(m2);     // m2 != 0 guaranteed by virtual pad

    int A = seq_len[b];

    f32x4 va = (f32x4)(0.0f);
    f32x4 vb = (f32x4)(0.0f);
    if (t < A && L > 0) {
        // wave-uniform length-regulator arithmetic
        int base  = (int)((unsigned)A / (unsigned)L);      // >= 2 here
        int rr    = A - base * L;
        int split = (L - rr) * base;
        int j;
        if (t < split) {
            j = (int)((unsigned)t / (unsigned)base);
        } else {
            j = (L - rr) + (int)((unsigned)(t - split) / (unsigned)(base + 1));
        }
        if (j > L - 1) j = L - 1;         // safety clamp (math guarantees j < L)
        int tok = trow[j] + 1;            // broadcast load, wave-uniform
        const f32x4* wr = W4 + (long)tok * D4;
        va = wr[lane];                    // 1 KB coalesced
        vb = wr[lane + 64];               // 1 KB coalesced, independent
    }
    f32x4* orow = out4 + (long)wid * D4;
    __builtin_nontemporal_store(va, &orow[lane]);
    __builtin_nontemporal_store(vb, &orow[lane + 64]);
}

extern "C" void kernel_launch(void* const* d_in, const int* in_sizes, int n_in,
                              void* d_out, int out_size, void* d_ws, size_t ws_size,
                              hipStream_t stream) {
    const int* text    = (const int*)d_in[0];
    const int* seq_len = (const int*)d_in[1];
    const f32x4* W4    = (const f32x4*)d_in[2];
    f32x4* out4        = (f32x4*)d_out;

    // one wave per output row: B*S waves = B*S/4 blocks of 256
    int nblocks = BB * SS / 4;            // 32768
    fused_upsample_kernel<<<nblocks, 256, 0, stream>>>(text, seq_len, W4, out4);
}